// Round 8
// baseline (188.698 us; speedup 1.0000x reference)
//
#include <hip/hip_runtime.h>
#include <hip/hip_bf16.h>

#define NSEQ   192
#define PADV   -1000.0f
#define NEGINF -1.0e30f

typedef __bf16 bf16x8 __attribute__((ext_vector_type(8)));
typedef float  f32x4  __attribute__((ext_vector_type(4)));

__device__ __forceinline__ void glds16(const void* g, void* l) {
  __builtin_amdgcn_global_load_lds(
      (const __attribute__((address_space(1))) unsigned int*)g,
      (__attribute__((address_space(3))) unsigned int*)l, 16, 0, 0);
}

#define MFMA16(a, b, c) __builtin_amdgcn_mfma_f32_16x16x32_bf16((a), (b), (c), 0, 0, 0)

// ---------------------------------------------------------------------------
// prep_pack: repack weights into bf16 MFMA fragment order (frag: lane l elem
// e holds M[k=(l>>4)*8+e][h=(l&15)+16q]); 12-frag padded slices; b1p tail.
// ---------------------------------------------------------------------------
__global__ __launch_bounds__(256) void prep_pack(const float* __restrict__ W1,
                                                 const float* __restrict__ W2,
                                                 const float* __restrict__ b1,
                                                 __bf16* __restrict__ W1abp,
                                                 __bf16* __restrict__ W1cp,
                                                 __bf16* __restrict__ W2p,
                                                 float* __restrict__ b1p) {
  int idx = blockIdx.x * 256 + threadIdx.x;   // grid 1657*256
  if (idx < 245760) {
    int e = idx & 7, l = (idx >> 3) & 63, t = idx >> 9;
    int ct = t % 20, kk = t / 20;             // kk 0..23
    int k = kk * 32 + ((l >> 4) << 3) + e;    // 0..767
    int hp = ct * 16 + (l & 15);              // 0..319
    int col = (hp < 160) ? hp : hp - 160;
    int rbase = (hp < 160) ? 0 : 768;
    float v = (col < 150) ? W1[(size_t)(rbase + k) * 150 + col] : 0.f;
    W1abp[idx] = (__bf16)v;
  } else if (idx < 393216) {
    int j = idx - 245760;
    int kk = j / 6144, rem = j % 6144;
    int q = rem >> 9, l = (rem >> 3) & 63, e = rem & 7;
    int k = kk * 32 + ((l >> 4) << 3) + e;
    int h = q * 16 + (l & 15);
    float v = (q < 10 && h < 150) ? W1[(size_t)(1536 + k) * 150 + h] : 0.f;
    W1cp[j] = (__bf16)v;
  } else if (idx < 423936) {
    int j = idx - 393216;                     // < 30720
    int s = j / 6144, rem = j % 6144;
    int q = rem >> 9, l = (rem >> 3) & 63, e = rem & 7;
    int k = s * 32 + ((l >> 4) << 3) + e;
    int h = q * 16 + (l & 15);
    float v = (q < 10 && k < 150 && h < 150) ? W2[(size_t)k * 150 + h] : 0.f;
    W2p[j] = (__bf16)v;
  } else if (idx < 424096) {
    int h = idx - 423936;
    b1p[h] = (h < 150) ? b1[h] : 0.f;
  }
}

// ---------------------------------------------------------------------------
// prep_gemm: A12[1536][320] += E @ [W1a|W1b], K split 8 ways (f32 atomics).
// ---------------------------------------------------------------------------
__global__ __launch_bounds__(256) void prep_gemm(const float* __restrict__ E,
                                                 const __bf16* __restrict__ W1abp,
                                                 float* __restrict__ A12) {
  int tid = threadIdx.x;
  int w = tid >> 6, l = tid & 63, m = l & 15, kg = l >> 4;
  int mt = blockIdx.x >> 3;                   // 0..95
  int c  = blockIdx.x & 7;                    // K-chunk 0..7
  const float* ep = E + (size_t)(mt * 16 + m) * 768 + c * 96;

  f32x4 acc[5];
#pragma unroll
  for (int u = 0; u < 5; ++u) acc[u] = (f32x4){0.f, 0.f, 0.f, 0.f};

#pragma unroll
  for (int kk = 0; kk < 3; ++kk) {
    int k = kk * 32 + kg * 8;
    f32x4 x0 = *(const f32x4*)(ep + k);
    f32x4 x1 = *(const f32x4*)(ep + k + 4);
    bf16x8 af;
#pragma unroll
    for (int e = 0; e < 4; ++e) { af[e] = (__bf16)x0[e]; af[e + 4] = (__bf16)x1[e]; }
    const bf16x8* wp = (const bf16x8*)W1abp + (size_t)(((c * 3 + kk) * 20) + w * 5) * 64 + l;
#pragma unroll
    for (int u = 0; u < 5; ++u)
      acc[u] = MFMA16(af, wp[u * 64], acc[u]);
  }
#pragma unroll
  for (int u = 0; u < 5; ++u)
#pragma unroll
    for (int r = 0; r < 4; ++r)
      atomicAdd(&A12[(size_t)(mt * 16 + kg * 4 + r) * 320 + (w * 5 + u) * 16 + m], acc[u][r]);
}

// ---------------------------------------------------------------------------
// pair_mlp: block = 16i x 8j tile, 256 threads / 4 waves, wave w owns j-cols
// {2w, 2w+1}. SINGLE-BARRIER free-running rounds: unified 34-tile stage
// stream (24 W1c + 5 W2 + 5 W2 re-staged), triple-buffered slots, counted
// vmcnt(3), ONE s_barrier per round, no trailing barrier. Swapped GEMM1
// C1[h][pair=i]; e_i/e_j bf16 in LDS chunk-XOR swizzled; h1 reuses dead eib.
// ---------------------------------------------------------------------------
__global__ __launch_bounds__(256) void pair_mlp(
    const float* __restrict__ E, const float* __restrict__ A12,
    const __bf16* __restrict__ W1cp, const __bf16* __restrict__ W2p,
    const float* __restrict__ b1p, const float* __restrict__ b2,
    const float* __restrict__ W3, const float* __restrict__ b3,
    float* __restrict__ out) {
  __shared__ alignas(16) char pool[75648];
  // [0,36864)      W slots: 3 x 12288B (12 frags x 1024B)
  // [36864,61440)  eib: 16 rows x 96 chunks(16B), XOR-swizzled; GEMM2: h1
  // [61440,73728)  ejb: 8 rows x 96 chunks(16B), XOR-swizzled
  // [73728,75648)  bw: b2f[160], w3f[160] f32
  char* eib = pool + 36864;
  char* ejb = pool + 61440;

  const int tid = threadIdx.x;
  const int w = tid >> 6, l = tid & 63;
  const int m = l & 15, kg = l >> 4;
  const int jr0 = 2 * w, jr1 = 2 * w + 1;

  // XCD-aware bijective swizzle (1248 == 8*156), then tri decode (16x8 tiles)
  int bid = blockIdx.x;
  int blk = (bid & 7) * 156 + (bid >> 3);
  int b = blk / 156, r0 = blk - b * 156;
  int it = (int)((sqrtf(4.f * (float)r0 + 1.f) - 1.f) * 0.5f);
  while (it * it + it > r0) --it;
  while ((it + 1) * (it + 1) + (it + 1) <= r0) ++it;
  int jt = r0 - it * it - it;                 // 0..2it+1

  const int ibase = b * NSEQ + it * 16;
  const int jbase = b * NSEQ + jt * 8;

  // ---- issue stage(0): W1c slice 0 into slot 0 (3 frags per wave) ----
  {
    const __bf16* src = W1cp + (size_t)(w * 3) * 512;
    char* dst = pool + (w * 3) * 1024;
#pragma unroll
    for (int q = 0; q < 3; ++q) glds16(src + q * 512 + l * 8, dst + q * 1024);
  }

  // ---- stage e_i (16 rows) + e_j (8 rows) as bf16, chunk-XOR swizzled ----
#pragma unroll
  for (int q = 0; q < 9; ++q) {
    int t = tid + 256 * q;                    // 0..2303
    int isI = (t < 1536);
    int tt = isI ? t : t - 1536;
    int r = tt / 96, d = tt - (tt / 96) * 96;
    int sc = d ^ (r & 7);
    const float* src = E + (size_t)((isI ? ibase : jbase) + r) * 768 + sc * 8;
    f32x4 a0 = *(const f32x4*)(src);
    f32x4 a1 = *(const f32x4*)(src + 4);
    bf16x8 v;
#pragma unroll
    for (int e = 0; e < 4; ++e) { v[e] = (__bf16)a0[e]; v[e + 4] = (__bf16)a1[e]; }
    *(bf16x8*)((isI ? eib : ejb) + r * 1536 + d * 16) = v;
  }

  // ---- stage b2/W3 (padded) ----
  if (tid < 160) {
    float* bwf = (float*)(pool + 73728);
    bwf[tid]       = (tid < 150) ? b2[tid] : 0.f;
    bwf[160 + tid] = (tid < 150) ? W3[tid] : 0.f;
  }
  float b3v = b3[0];

  // ---- acc1 init: C1[h][pair] = A1[i=m][h] + A2[j][h] + b1[h] ----
  f32x4 acc1[10][2];
#pragma unroll
  for (int ct = 0; ct < 10; ++ct) {
    f32x4 a1v = *(const f32x4*)(A12 + (size_t)(ibase + m) * 320 + ct * 16 + kg * 4);
    f32x4 b1v = *(const f32x4*)(b1p + ct * 16 + kg * 4);
#pragma unroll
    for (int pt = 0; pt < 2; ++pt) {
      f32x4 a2v = *(const f32x4*)(A12 + (size_t)(jbase + jr0 + pt) * 320 + 160 + ct * 16 + kg * 4);
      acc1[ct][pt] = a1v + a2v + b1v;
    }
  }

  __syncthreads();   // drains stage(0), e-writes, bw

  char* hb = pool + 36864 + w * 6144;         // wave-private h1 (reuses eib)
  f32x4 acc2[10];

  auto write_h1 = [&](int p) {
#pragma unroll
    for (int ct = 0; ct < 10; ++ct) {
      union { __bf16 h[4]; unsigned u[2]; } cv;
      cv.h[0] = (__bf16)fmaxf(acc1[ct][p][0], 0.f);
      cv.h[1] = (__bf16)fmaxf(acc1[ct][p][1], 0.f);
      cv.h[2] = (__bf16)fmaxf(acc1[ct][p][2], 0.f);
      cv.h[3] = (__bf16)fmaxf(acc1[ct][p][3], 0.f);
      int c = (2 * ct + (kg >> 1)) ^ (m & 7);
      char* dst = hb + m * 384 + c * 16 + (kg & 1) * 8;
      *(unsigned*)(dst)     = cv.u[0];
      *(unsigned*)(dst + 4) = cv.u[1];
    }
  };

  const float* bwp = (const float*)(pool + 73728);

  // ---- unified main loop: 34 rounds, ONE barrier each ----
  for (int t = 0; t < 34; ++t) {
    // issue stage(t+1) into slot (t+1)%3
    if (t < 33) {
      int tn = t + 1;
      const __bf16* src = (tn < 24)
          ? (W1cp + ((size_t)tn * 12 + w * 3) * 512)
          : (W2p + ((size_t)((tn - 24) % 5) * 12 + w * 3) * 512);
      char* dst = pool + (tn % 3) * 12288 + (w * 3) * 1024;
#pragma unroll
      for (int q = 0; q < 3; ++q) glds16(src + q * 512 + l * 8, dst + q * 1024);
      asm volatile("s_waitcnt vmcnt(3)" ::: "memory");
    } else {
      asm volatile("s_waitcnt vmcnt(0)" ::: "memory");
    }
    __builtin_amdgcn_s_barrier();

    const __bf16* wb = (const __bf16*)(pool + (t % 3) * 12288);

    if (t < 24) {
      // GEMM1 k-step
      int cb = t * 4 + kg;
      bf16x8 eiv = *(const bf16x8*)(eib + m * 1536 + ((cb ^ (m & 7)) << 4));
      bf16x8 ej0 = *(const bf16x8*)(ejb + jr0 * 1536 + ((cb ^ (jr0 & 7)) << 4));
      bf16x8 ej1 = *(const bf16x8*)(ejb + jr1 * 1536 + ((cb ^ (jr1 & 7)) << 4));
      bf16x8 pf0, pf1;
#pragma unroll
      for (int e = 0; e < 8; ++e) {
        float ei = (float)eiv[e];
        pf0[e] = (__bf16)(ei * (float)ej0[e]);
        pf1[e] = (__bf16)(ei * (float)ej1[e]);
      }
      __builtin_amdgcn_s_setprio(1);
#pragma unroll
      for (int ct = 0; ct < 10; ++ct) {
        bf16x8 wf = *(const bf16x8*)(wb + ct * 512 + l * 8);
        acc1[ct][0] = MFMA16(wf, pf0, acc1[ct][0]);
        acc1[ct][1] = MFMA16(wf, pf1, acc1[ct][1]);
      }
      __builtin_amdgcn_s_setprio(0);
    } else {
      // GEMM2 round: pass p (j = 2w+p), slice s
      int r = t - 24;
      int p = (r >= 5) ? 1 : 0;
      int s = r - p * 5;
      if (s == 0) {
        write_h1(p);   // safe: barrier(24)/(29) => all eib reads done
#pragma unroll
        for (int ct = 0; ct < 10; ++ct) acc2[ct] = (f32x4){0.f, 0.f, 0.f, 0.f};
      }
      bf16x8 af = *(const bf16x8*)(hb + m * 384 + (((4 * s + kg) ^ (m & 7)) << 4));
      __builtin_amdgcn_s_setprio(1);
#pragma unroll
      for (int ct = 0; ct < 10; ++ct) {
        bf16x8 wf = *(const bf16x8*)(wb + ct * 512 + l * 8);
        acc2[ct] = MFMA16(wf, af, acc2[ct]);
      }
      __builtin_amdgcn_s_setprio(0);

      if (s == 4) {   // pass epilogue: fold + cross-kg reduce + store
        float sum = 0.f;
#pragma unroll
        for (int ct = 0; ct < 10; ++ct) {
          f32x4 b2q = *(const f32x4*)(bwp + ct * 16 + kg * 4);
          f32x4 w3q = *(const f32x4*)(bwp + 160 + ct * 16 + kg * 4);
#pragma unroll
          for (int r2 = 0; r2 < 4; ++r2)
            sum += fmaxf(acc2[ct][r2] + b2q[r2], 0.f) * w3q[r2];
        }
        sum += __shfl_xor(sum, 16, 64);
        sum += __shfl_xor(sum, 32, 64);
        if (kg == 0) {
          int il = it * 16 + m;
          int jl = jt * 8 + 2 * w + p;
          if (jl < il)
            out[(size_t)(b * NSEQ + il) * NSEQ + jl] = sum + b3v;
        }
      }
    }
  }
}

// ---------------------------------------------------------------------------
// softmax: 4 (b,i)-rows per block, one wave each.
// ---------------------------------------------------------------------------
__global__ __launch_bounds__(256) void softmax_rows(float* __restrict__ out) {
  int w = threadIdx.x >> 6, l = threadIdx.x & 63;
  int blk = blockIdx.x * 4 + w;   // 0..1535 = b*192+i
  int i = blk % NSEQ;
  size_t base = (size_t)blk * NSEQ;
  float v[3];
  float mx = NEGINF;
#pragma unroll
  for (int t = 0; t < 3; ++t) {
    int j = l + 64 * t;
    float x = (j < i) ? out[base + j] : (j == i ? 0.f : NEGINF);
    v[t] = x;
    mx = fmaxf(mx, x);
  }
#pragma unroll
  for (int off = 32; off >= 1; off >>= 1) mx = fmaxf(mx, __shfl_xor(mx, off, 64));
  float s = 0.f;
#pragma unroll
  for (int t = 0; t < 3; ++t) s += __expf(v[t] - mx);
#pragma unroll
  for (int off = 32; off >= 1; off >>= 1) s += __shfl_xor(s, off, 64);
  float inv = 1.0f / s;
#pragma unroll
  for (int t = 0; t < 3; ++t) {
    int j = l + 64 * t;
    out[base + j] = (j <= i) ? __expf(v[t] - mx) * inv : PADV;
  }
}

// ---------------------------------------------------------------------------
extern "C" void kernel_launch(void* const* d_in, const int* in_sizes, int n_in,
                              void* d_out, int out_size, void* d_ws, size_t ws_size,
                              hipStream_t stream) {
  const float* E  = (const float*)d_in[0];
  const float* W1 = (const float*)d_in[1];
  const float* b1 = (const float*)d_in[2];
  const float* W2 = (const float*)d_in[3];
  const float* b2 = (const float*)d_in[4];
  const float* W3 = (const float*)d_in[5];
  const float* b3 = (const float*)d_in[6];
  float* out = (float*)d_out;

  char* ws = (char*)d_ws;
  float*  A12   = (float*)(ws);                 // 1,966,080 B
  __bf16* W1abp = (__bf16*)(ws + 1966080);      //   491,520 B
  __bf16* W1cp  = (__bf16*)(ws + 2457600);      //   294,912 B (12-frag padded)
  __bf16* W2p   = (__bf16*)(ws + 2752512);      //    61,440 B (12-frag padded)
  float*  b1p   = (float*)(ws + 2813952);       //       640 B

  hipMemsetAsync(A12, 0, 1966080, stream);
  prep_pack<<<1657, 256, 0, stream>>>(W1, W2, b1, W1abp, W1cp, W2p, b1p);
  prep_gemm<<<768, 256, 0, stream>>>(E, W1abp, A12);
  pair_mlp<<<1248, 256, 0, stream>>>(E, A12, W1cp, W2p, b1p, b2, W3, b3, out);
  softmax_rows<<<384, 256, 0, stream>>>(out);
}

// Round 9
// 113.273 us; speedup vs baseline: 1.6659x; 1.6659x over previous
//
#include <hip/hip_runtime.h>
#include <hip/hip_bf16.h>

#define NSEQ   192
#define PADV   -1000.0f
#define NEGINF -1.0e30f

typedef __bf16 bf16x8 __attribute__((ext_vector_type(8)));
typedef float  f32x4  __attribute__((ext_vector_type(4)));

__device__ __forceinline__ void glds16(const void* g, void* l) {
  __builtin_amdgcn_global_load_lds(
      (const __attribute__((address_space(1))) unsigned int*)g,
      (__attribute__((address_space(3))) unsigned int*)l, 16, 0, 0);
}

#define MFMA16(a, b, c) __builtin_amdgcn_mfma_f32_16x16x32_bf16((a), (b), (c), 0, 0, 0)

// ---------------------------------------------------------------------------
// prep_pack: repack weights into bf16 MFMA fragment order (frag: lane l elem
// e holds M[k=(l>>4)*8+e][h=(l&15)+16q]); 12-frag padded slices; b1p tail.
// ---------------------------------------------------------------------------
__global__ __launch_bounds__(256) void prep_pack(const float* __restrict__ W1,
                                                 const float* __restrict__ W2,
                                                 const float* __restrict__ b1,
                                                 __bf16* __restrict__ W1abp,
                                                 __bf16* __restrict__ W1cp,
                                                 __bf16* __restrict__ W2p,
                                                 float* __restrict__ b1p) {
  int idx = blockIdx.x * 256 + threadIdx.x;   // grid 1657*256
  if (idx < 245760) {
    int e = idx & 7, l = (idx >> 3) & 63, t = idx >> 9;
    int ct = t % 20, kk = t / 20;             // kk 0..23
    int k = kk * 32 + ((l >> 4) << 3) + e;    // 0..767
    int hp = ct * 16 + (l & 15);              // 0..319
    int col = (hp < 160) ? hp : hp - 160;
    int rbase = (hp < 160) ? 0 : 768;
    float v = (col < 150) ? W1[(size_t)(rbase + k) * 150 + col] : 0.f;
    W1abp[idx] = (__bf16)v;
  } else if (idx < 393216) {
    int j = idx - 245760;
    int kk = j / 6144, rem = j % 6144;
    int q = rem >> 9, l = (rem >> 3) & 63, e = rem & 7;
    int k = kk * 32 + ((l >> 4) << 3) + e;
    int h = q * 16 + (l & 15);
    float v = (q < 10 && h < 150) ? W1[(size_t)(1536 + k) * 150 + h] : 0.f;
    W1cp[j] = (__bf16)v;
  } else if (idx < 423936) {
    int j = idx - 393216;                     // < 30720
    int s = j / 6144, rem = j % 6144;
    int q = rem >> 9, l = (rem >> 3) & 63, e = rem & 7;
    int k = s * 32 + ((l >> 4) << 3) + e;
    int h = q * 16 + (l & 15);
    float v = (q < 10 && k < 150 && h < 150) ? W2[(size_t)k * 150 + h] : 0.f;
    W2p[j] = (__bf16)v;
  } else if (idx < 424096) {
    int h = idx - 423936;
    b1p[h] = (h < 150) ? b1[h] : 0.f;
  }
}

// ---------------------------------------------------------------------------
// prep_gemm: A12[1536][320] += E @ [W1a|W1b], K split 8 ways (f32 atomics).
// ---------------------------------------------------------------------------
__global__ __launch_bounds__(256) void prep_gemm(const float* __restrict__ E,
                                                 const __bf16* __restrict__ W1abp,
                                                 float* __restrict__ A12) {
  int tid = threadIdx.x;
  int w = tid >> 6, l = tid & 63, m = l & 15, kg = l >> 4;
  int mt = blockIdx.x >> 3;                   // 0..95
  int c  = blockIdx.x & 7;                    // K-chunk 0..7
  const float* ep = E + (size_t)(mt * 16 + m) * 768 + c * 96;

  f32x4 acc[5];
#pragma unroll
  for (int u = 0; u < 5; ++u) acc[u] = (f32x4){0.f, 0.f, 0.f, 0.f};

#pragma unroll
  for (int kk = 0; kk < 3; ++kk) {
    int k = kk * 32 + kg * 8;
    f32x4 x0 = *(const f32x4*)(ep + k);
    f32x4 x1 = *(const f32x4*)(ep + k + 4);
    bf16x8 af;
#pragma unroll
    for (int e = 0; e < 4; ++e) { af[e] = (__bf16)x0[e]; af[e + 4] = (__bf16)x1[e]; }
    const bf16x8* wp = (const bf16x8*)W1abp + (size_t)(((c * 3 + kk) * 20) + w * 5) * 64 + l;
#pragma unroll
    for (int u = 0; u < 5; ++u)
      acc[u] = MFMA16(af, wp[u * 64], acc[u]);
  }
#pragma unroll
  for (int u = 0; u < 5; ++u)
#pragma unroll
    for (int r = 0; r < 4; ++r)
      atomicAdd(&A12[(size_t)(mt * 16 + kg * 4 + r) * 320 + (w * 5 + u) * 16 + m], acc[u][r]);
}

// ---------------------------------------------------------------------------
// pair_mlp r9: 16i x 8j tile, 256 thr / 4 waves, wave owns j {2w,2w+1}.
// Register-software-pipelined rounds: W slots triple-buffered, staged TWO
// tiles ahead (vmcnt(3) counted); per round: ONE raw s_barrier; ds_read
// NEXT round's W/e/h1 frags into regs while MFMAing on regs prefetched last
// round. Fully unrolled (static slot indices). No setprio. Stores at end.
// Tile stream: 0..23 = W1c slices, 24..33 = W2 slices (x2 passes).
// ---------------------------------------------------------------------------
__global__ __launch_bounds__(256) void pair_mlp(
    const float* __restrict__ E, const float* __restrict__ A12,
    const __bf16* __restrict__ W1cp, const __bf16* __restrict__ W2p,
    const float* __restrict__ b1p, const float* __restrict__ b2,
    const float* __restrict__ W3, const float* __restrict__ b3,
    float* __restrict__ out) {
  __shared__ alignas(16) char pool[75648];
  // [0,36864)      W slots: 3 x 12288B (12 frags x 1024B)
  // [36864,61440)  eib: 16 rows x 96 chunks(16B), XOR-swizzled; GEMM2: h1
  // [61440,73728)  ejb: 8 rows x 96 chunks(16B), XOR-swizzled
  // [73728,75648)  bw: b2f[160], w3f[160] f32
  char* eib = pool + 36864;
  char* ejb = pool + 61440;

  const int tid = threadIdx.x;
  const int w = tid >> 6, l = tid & 63;
  const int m = l & 15, kg = l >> 4;
  const int jr0 = 2 * w, jr1 = 2 * w + 1;

  // XCD-aware bijective swizzle (1248 == 8*156), tri decode (16x8 tiles)
  int bid = blockIdx.x;
  int blk = (bid & 7) * 156 + (bid >> 3);
  int b = blk / 156, r0 = blk - b * 156;
  int it = (int)((sqrtf(4.f * (float)r0 + 1.f) - 1.f) * 0.5f);
  while (it * it + it > r0) --it;
  while ((it + 1) * (it + 1) + (it + 1) <= r0) ++it;
  int jt = r0 - it * it - it;                 // 0..2it+1

  const int ibase = b * NSEQ + it * 16;
  const int jbase = b * NSEQ + jt * 8;

  // ---- issue stages for tiles 0 and 1 FIRST (oldest in vm queue) ----
#pragma unroll
  for (int tt = 0; tt < 2; ++tt) {
    const __bf16* src = W1cp + ((size_t)tt * 12 + w * 3) * 512;
    char* dst = pool + tt * 12288 + (w * 3) * 1024;
#pragma unroll
    for (int q = 0; q < 3; ++q) glds16(src + q * 512 + l * 8, dst + q * 1024);
  }

  // ---- stage e_i (16 rows) + e_j (8 rows) as bf16, chunk-XOR swizzled ----
#pragma unroll
  for (int q = 0; q < 9; ++q) {
    int t = tid + 256 * q;                    // 0..2303
    int isI = (t < 1536);
    int tt = isI ? t : t - 1536;
    int r = tt / 96, d = tt - (tt / 96) * 96;
    int sc = d ^ (r & 7);
    const float* src = E + (size_t)((isI ? ibase : jbase) + r) * 768 + sc * 8;
    f32x4 a0 = *(const f32x4*)(src);
    f32x4 a1 = *(const f32x4*)(src + 4);
    bf16x8 v;
#pragma unroll
    for (int e = 0; e < 4; ++e) { v[e] = (__bf16)a0[e]; v[e + 4] = (__bf16)a1[e]; }
    *(bf16x8*)((isI ? eib : ejb) + r * 1536 + d * 16) = v;
  }

  // ---- stage b2/W3 (padded) ----
  if (tid < 160) {
    float* bwf = (float*)(pool + 73728);
    bwf[tid]       = (tid < 150) ? b2[tid] : 0.f;
    bwf[160 + tid] = (tid < 150) ? W3[tid] : 0.f;
  }
  float b3v = b3[0];

  // ---- acc1 init: C1[h][pair] = A1[i=m][h] + A2[j][h] + b1[h] ----
  f32x4 acc1[10][2];
#pragma unroll
  for (int ct = 0; ct < 10; ++ct) {
    f32x4 a1v = *(const f32x4*)(A12 + (size_t)(ibase + m) * 320 + ct * 16 + kg * 4);
    f32x4 b1v = *(const f32x4*)(b1p + ct * 16 + kg * 4);
#pragma unroll
    for (int pt = 0; pt < 2; ++pt) {
      f32x4 a2v = *(const f32x4*)(A12 + (size_t)(jbase + jr0 + pt) * 320 + 160 + ct * 16 + kg * 4);
      acc1[ct][pt] = a1v + a2v + b1v;
    }
  }

  // raw barrier (NOT __syncthreads: that would drain vmcnt(0) and kill the
  // tile-1 in-flight stage). lgkmcnt(0) covers the e/bw LDS writes.
  asm volatile("s_waitcnt vmcnt(3) lgkmcnt(0)" ::: "memory");
  __builtin_amdgcn_s_barrier();

  // ---- register prefetch: W tile 0 + e step 0 ----
  auto ldw = [&](int slot, int ct) -> bf16x8 {
    return *(const bf16x8*)(pool + slot * 12288 + ct * 1024 + l * 16);
  };
  auto ldei = [&](int step) -> bf16x8 {
    int cb = step * 4 + kg;
    return *(const bf16x8*)(eib + m * 1536 + ((cb ^ (m & 7)) << 4));
  };
  auto ldej = [&](int jr, int step) -> bf16x8 {
    int cb = step * 4 + kg;
    return *(const bf16x8*)(ejb + jr * 1536 + ((cb ^ (jr & 7)) << 4));
  };

  bf16x8 wC[10];
#pragma unroll
  for (int ct = 0; ct < 10; ++ct) wC[ct] = ldw(0, ct);
  bf16x8 eiC = ldei(0), ej0C = ldej(jr0, 0), ej1C = ldej(jr1, 0);

  // ---- GEMM1: 24 rounds, fully unrolled ----
#pragma unroll
  for (int t = 0; t < 24; ++t) {
    {   // stage tile t+2 into slot (t+2)%3
      int tn = t + 2;
      const __bf16* src = (tn < 24)
          ? (W1cp + ((size_t)tn * 12 + w * 3) * 512)
          : (W2p + ((size_t)(tn - 24) * 12 + w * 3) * 512);
      char* dst = pool + (tn % 3) * 12288 + (w * 3) * 1024;
#pragma unroll
      for (int q = 0; q < 3; ++q) glds16(src + q * 512 + l * 8, dst + q * 1024);
    }
    asm volatile("s_waitcnt vmcnt(3)" ::: "memory");   // tile t+1 resident
    __builtin_amdgcn_s_barrier();

    // prefetch next round's operands (reads overlap this round's MFMAs)
    bf16x8 wN[10];
#pragma unroll
    for (int ct = 0; ct < 10; ++ct) wN[ct] = ldw((t + 1) % 3, ct);
    bf16x8 eiN, ej0N, ej1N;
    if (t < 23) { eiN = ldei(t + 1); ej0N = ldej(jr0, t + 1); ej1N = ldej(jr1, t + 1); }

    // pack + 20 MFMA on current regs
    bf16x8 pf0, pf1;
#pragma unroll
    for (int e = 0; e < 8; ++e) {
      float ei = (float)eiC[e];
      pf0[e] = (__bf16)(ei * (float)ej0C[e]);
      pf1[e] = (__bf16)(ei * (float)ej1C[e]);
    }
#pragma unroll
    for (int ct = 0; ct < 10; ++ct) {
      acc1[ct][0] = MFMA16(wC[ct], pf0, acc1[ct][0]);
      acc1[ct][1] = MFMA16(wC[ct], pf1, acc1[ct][1]);
    }
#pragma unroll
    for (int ct = 0; ct < 10; ++ct) wC[ct] = wN[ct];
    if (t < 23) { eiC = eiN; ej0C = ej0N; ej1C = ej1N; }
  }

  // ---- GEMM2: 10 rounds (2 passes x 5 slices), fully unrolled ----
  char* hb = pool + 36864 + w * 6144;         // wave-private h1 (reuses eib)
  const float* bwp = (const float*)(pool + 73728);

  auto write_h1 = [&](int p) {
#pragma unroll
    for (int ct = 0; ct < 10; ++ct) {
      union { __bf16 h[4]; unsigned u[2]; } cv;
      cv.h[0] = (__bf16)fmaxf(acc1[ct][p][0], 0.f);
      cv.h[1] = (__bf16)fmaxf(acc1[ct][p][1], 0.f);
      cv.h[2] = (__bf16)fmaxf(acc1[ct][p][2], 0.f);
      cv.h[3] = (__bf16)fmaxf(acc1[ct][p][3], 0.f);
      int c = (2 * ct + (kg >> 1)) ^ (m & 7);
      char* dst = hb + m * 384 + c * 16 + (kg & 1) * 8;
      *(unsigned*)(dst)     = cv.u[0];
      *(unsigned*)(dst + 4) = cv.u[1];
    }
  };
  auto ldaf = [&](int s) -> bf16x8 {
    return *(const bf16x8*)(hb + m * 384 + (((4 * s + kg) ^ (m & 7)) << 4));
  };

  f32x4 acc2[10];
  bf16x8 afC;
  float sum0 = 0.f, sum1 = 0.f;

#pragma unroll
  for (int r = 0; r < 10; ++r) {
    int t = 24 + r;
    if (t + 2 <= 33) {   // stage tile t+2 (W2 slice (t+2-24)%5)
      int tn = t + 2;
      const __bf16* src = W2p + ((size_t)((tn - 24) % 5) * 12 + w * 3) * 512;
      char* dst = pool + (tn % 3) * 12288 + (w * 3) * 1024;
#pragma unroll
      for (int q = 0; q < 3; ++q) glds16(src + q * 512 + l * 8, dst + q * 1024);
      asm volatile("s_waitcnt vmcnt(3)" ::: "memory");
    } else {
      asm volatile("s_waitcnt vmcnt(0)" ::: "memory");
    }
    __builtin_amdgcn_s_barrier();

    // prefetch next round's W
    bf16x8 wN[10];
    if (r < 9) {
#pragma unroll
      for (int ct = 0; ct < 10; ++ct) wN[ct] = ldw((t + 1) % 3, ct);
    }

    int p = r / 5, s = r - p * 5;
    if (s == 0) {
      write_h1(p);            // same-wave DS order: write then read is safe
      afC = ldaf(0);
#pragma unroll
      for (int ct = 0; ct < 10; ++ct) acc2[ct] = (f32x4){0.f, 0.f, 0.f, 0.f};
    }
    bf16x8 afN;
    if (s < 4) afN = ldaf(s + 1);

#pragma unroll
    for (int ct = 0; ct < 10; ++ct)
      acc2[ct] = MFMA16(wC[ct], afC, acc2[ct]);

    if (s == 4) {   // pass epilogue: fold + cross-kg reduce (store deferred)
      float sum = 0.f;
#pragma unroll
      for (int ct = 0; ct < 10; ++ct) {
        f32x4 b2q = *(const f32x4*)(bwp + ct * 16 + kg * 4);
        f32x4 w3q = *(const f32x4*)(bwp + 160 + ct * 16 + kg * 4);
#pragma unroll
        for (int r2 = 0; r2 < 4; ++r2)
          sum += fmaxf(acc2[ct][r2] + b2q[r2], 0.f) * w3q[r2];
      }
      sum += __shfl_xor(sum, 16, 64);
      sum += __shfl_xor(sum, 32, 64);
      if (p == 0) sum0 = sum; else sum1 = sum;
    } else {
      afC = afN;
    }
    if (r < 9) {
#pragma unroll
      for (int ct = 0; ct < 10; ++ct) wC[ct] = wN[ct];
    }
  }

  // ---- deferred stores (keep vmcnt stream clean inside the loop) ----
  if (kg == 0) {
    int il = it * 16 + m;
    int jl0 = jt * 8 + 2 * w;
    if (jl0 < il)     out[(size_t)(b * NSEQ + il) * NSEQ + jl0]     = sum0 + b3v;
    if (jl0 + 1 < il) out[(size_t)(b * NSEQ + il) * NSEQ + jl0 + 1] = sum1 + b3v;
  }
}

// ---------------------------------------------------------------------------
// softmax: 4 (b,i)-rows per block, one wave each.
// ---------------------------------------------------------------------------
__global__ __launch_bounds__(256) void softmax_rows(float* __restrict__ out) {
  int w = threadIdx.x >> 6, l = threadIdx.x & 63;
  int blk = blockIdx.x * 4 + w;   // 0..1535 = b*192+i
  int i = blk % NSEQ;
  size_t base = (size_t)blk * NSEQ;
  float v[3];
  float mx = NEGINF;
#pragma unroll
  for (int t = 0; t < 3; ++t) {
    int j = l + 64 * t;
    float x = (j < i) ? out[base + j] : (j == i ? 0.f : NEGINF);
    v[t] = x;
    mx = fmaxf(mx, x);
  }
#pragma unroll
  for (int off = 32; off >= 1; off >>= 1) mx = fmaxf(mx, __shfl_xor(mx, off, 64));
  float s = 0.f;
#pragma unroll
  for (int t = 0; t < 3; ++t) s += __expf(v[t] - mx);
#pragma unroll
  for (int off = 32; off >= 1; off >>= 1) s += __shfl_xor(s, off, 64);
  float inv = 1.0f / s;
#pragma unroll
  for (int t = 0; t < 3; ++t) {
    int j = l + 64 * t;
    out[base + j] = (j <= i) ? __expf(v[t] - mx) * inv : PADV;
  }
}

// ---------------------------------------------------------------------------
extern "C" void kernel_launch(void* const* d_in, const int* in_sizes, int n_in,
                              void* d_out, int out_size, void* d_ws, size_t ws_size,
                              hipStream_t stream) {
  const float* E  = (const float*)d_in[0];
  const float* W1 = (const float*)d_in[1];
  const float* b1 = (const float*)d_in[2];
  const float* W2 = (const float*)d_in[3];
  const float* b2 = (const float*)d_in[4];
  const float* W3 = (const float*)d_in[5];
  const float* b3 = (const float*)d_in[6];
  float* out = (float*)d_out;

  char* ws = (char*)d_ws;
  float*  A12   = (float*)(ws);                 // 1,966,080 B
  __bf16* W1abp = (__bf16*)(ws + 1966080);      //   491,520 B
  __bf16* W1cp  = (__bf16*)(ws + 2457600);      //   294,912 B (12-frag padded)
  __bf16* W2p   = (__bf16*)(ws + 2752512);      //    61,440 B (12-frag padded)
  float*  b1p   = (float*)(ws + 2813952);       //       640 B

  hipMemsetAsync(A12, 0, 1966080, stream);
  prep_pack<<<1657, 256, 0, stream>>>(W1, W2, b1, W1abp, W1cp, W2p, b1p);
  prep_gemm<<<768, 256, 0, stream>>>(E, W1abp, A12);
  pair_mlp<<<1248, 256, 0, stream>>>(E, A12, W1cp, W2p, b1p, b2, W3, b3, out);
  softmax_rows<<<384, 256, 0, stream>>>(out);
}

// Round 10
// 106.129 us; speedup vs baseline: 1.7780x; 1.0673x over previous
//
#include <hip/hip_runtime.h>
#include <hip/hip_bf16.h>

#define NSEQ   192
#define PADV   -1000.0f
#define NEGINF -1.0e30f

typedef __bf16 bf16x8 __attribute__((ext_vector_type(8)));
typedef float  f32x4  __attribute__((ext_vector_type(4)));

__device__ __forceinline__ void glds16(const void* g, void* l) {
  __builtin_amdgcn_global_load_lds(
      (const __attribute__((address_space(1))) unsigned int*)g,
      (__attribute__((address_space(3))) unsigned int*)l, 16, 0, 0);
}

#define MFMA16(a, b, c) __builtin_amdgcn_mfma_f32_16x16x32_bf16((a), (b), (c), 0, 0, 0)

// ---------------------------------------------------------------------------
// prep_pack: repack weights into bf16 MFMA fragment order (frag: lane l elem
// e holds M[k=(l>>4)*8+e][h=(l&15)+16q]). Dense 10-frag slices for W1c/W2.
// Also zeroes A12 (drops the memset launch) and pads b1 -> b1p[160].
// ---------------------------------------------------------------------------
__global__ __launch_bounds__(256) void prep_pack(const float* __restrict__ W1,
                                                 const float* __restrict__ W2,
                                                 const float* __restrict__ b1,
                                                 __bf16* __restrict__ W1abp,
                                                 __bf16* __restrict__ W1cp,
                                                 __bf16* __restrict__ W2p,
                                                 float* __restrict__ b1p,
                                                 float* __restrict__ A12) {
  int idx = blockIdx.x * 256 + threadIdx.x;   // grid 1541*256 = 394496
  if (idx < 394240) A12[idx] = 0.f;
  if (idx < 97280)  A12[394240 + idx] = 0.f;

  if (idx < 245760) {
    int e = idx & 7, l = (idx >> 3) & 63, t = idx >> 9;
    int ct = t % 20, kk = t / 20;             // kk 0..23
    int k = kk * 32 + ((l >> 4) << 3) + e;    // 0..767
    int hp = ct * 16 + (l & 15);              // 0..319
    int col = (hp < 160) ? hp : hp - 160;
    int rbase = (hp < 160) ? 0 : 768;
    float v = (col < 150) ? W1[(size_t)(rbase + k) * 150 + col] : 0.f;
    W1abp[idx] = (__bf16)v;
  } else if (idx < 368640) {
    int j = idx - 245760;                     // < 122880 (24 kk x 10 ct)
    int e = j & 7, l = (j >> 3) & 63, t = j >> 9;
    int ct = t % 10, kk = t / 10;
    int k = kk * 32 + ((l >> 4) << 3) + e;
    int h = ct * 16 + (l & 15);
    float v = (h < 150) ? W1[(size_t)(1536 + k) * 150 + h] : 0.f;
    W1cp[j] = (__bf16)v;
  } else if (idx < 394240) {
    int j = idx - 368640;                     // < 25600 (5 s x 10 ct)
    int e = j & 7, l = (j >> 3) & 63, t = j >> 9;
    int ct = t % 10, s = t / 10;
    int k = s * 32 + ((l >> 4) << 3) + e;
    int h = ct * 16 + (l & 15);
    float v = (k < 150 && h < 150) ? W2[(size_t)k * 150 + h] : 0.f;
    W2p[j] = (__bf16)v;
  } else if (idx < 394400) {
    int h = idx - 394240;
    b1p[h] = (h < 150) ? b1[h] : 0.f;
  }
}

// ---------------------------------------------------------------------------
// prep_gemm: A12[1536][320] += E @ [W1a|W1b], K split 8 ways (f32 atomics).
// ---------------------------------------------------------------------------
__global__ __launch_bounds__(256) void prep_gemm(const float* __restrict__ E,
                                                 const __bf16* __restrict__ W1abp,
                                                 float* __restrict__ A12) {
  int tid = threadIdx.x;
  int w = tid >> 6, l = tid & 63, m = l & 15, kg = l >> 4;
  int mt = blockIdx.x >> 3;                   // 0..95
  int c  = blockIdx.x & 7;                    // K-chunk 0..7
  const float* ep = E + (size_t)(mt * 16 + m) * 768 + c * 96;

  f32x4 acc[5];
#pragma unroll
  for (int u = 0; u < 5; ++u) acc[u] = (f32x4){0.f, 0.f, 0.f, 0.f};

#pragma unroll
  for (int kk = 0; kk < 3; ++kk) {
    int k = kk * 32 + kg * 8;
    f32x4 x0 = *(const f32x4*)(ep + k);
    f32x4 x1 = *(const f32x4*)(ep + k + 4);
    bf16x8 af;
#pragma unroll
    for (int e = 0; e < 4; ++e) { af[e] = (__bf16)x0[e]; af[e + 4] = (__bf16)x1[e]; }
    const bf16x8* wp = (const bf16x8*)W1abp + (size_t)(((c * 3 + kk) * 20) + w * 5) * 64 + l;
#pragma unroll
    for (int u = 0; u < 5; ++u)
      acc[u] = MFMA16(af, wp[u * 64], acc[u]);
  }
#pragma unroll
  for (int u = 0; u < 5; ++u)
#pragma unroll
    for (int r = 0; r < 4; ++r)
      atomicAdd(&A12[(size_t)(mt * 16 + kg * 4 + r) * 320 + (w * 5 + u) * 16 + m], acc[u][r]);
}

// ---------------------------------------------------------------------------
// pair_mlp r10: 16i x 16j tile (624 blocks), 256 thr / 4 waves, wave w owns
// j-cols {4w..4w+3}. Swapped GEMM1 C1[h][i]: one W-frag read feeds 4 MFMAs
// (e_j reads wave-uniform broadcast; e_i per-lane row m, XOR-swizzled).
// BK=64 rounds (12), r5's proven 2-barrier + counted vmcnt(5) dbuf schedule,
// NO setprio. GEMM2: all of W2 resident once; h1 (all 4 j) wave-private,
// packed 8B writes; 5 barrier-free fat rounds; stores at end.
// ---------------------------------------------------------------------------
__global__ __launch_bounds__(256) void pair_mlp(
    const float* __restrict__ E, const float* __restrict__ A12,
    const __bf16* __restrict__ W1cp, const __bf16* __restrict__ W2p,
    const float* __restrict__ b1p, const float* __restrict__ b2,
    const float* __restrict__ W3, const float* __restrict__ b3,
    float* __restrict__ out) {
  __shared__ alignas(16) char pool[149504];
  // phase1: slabs [0,40960) = 2 x 20 frags x 1024B; eib [40960,65536) 16 rows
  //         x 1536B XOR-swizzled; ejb [65536,90112) 16 rows x 1536B swizzled;
  //         bw [90112,91392) b2f[160],w3f[160].
  // phase2: W2 resident [0,51200) 50 frags; h1 [51200,149504) = 16 (w,pt)
  //         slots x 6144B (16 pair-rows x 384B, chunk-XOR swizzled).
  char* eib = pool + 40960;
  char* ejb = pool + 65536;

  const int tid = threadIdx.x;
  const int w = tid >> 6, l = tid & 63;
  const int m = l & 15, kg = l >> 4;

  // XCD-aware bijective swizzle (624 == 8*78), tri decode (16x16 tiles)
  int bid = blockIdx.x;
  int blk = (bid & 7) * 78 + (bid >> 3);
  int b = blk / 78, r0 = blk - b * 78;
  int it = (int)((sqrtf(8.f * (float)r0 + 1.f) - 1.f) * 0.5f);
  while (it * (it + 1) / 2 > r0) --it;
  while ((it + 1) * (it + 2) / 2 <= r0) ++it;
  int jt = r0 - it * (it + 1) / 2;            // 0..it

  const int ibase = b * NSEQ + it * 16;
  const int jbase = b * NSEQ + jt * 16;

  // ---- stage W1c slab 0 (frags 0..19) into buf0 ----
#pragma unroll
  for (int q = 0; q < 5; ++q)
    glds16(W1cp + (size_t)(w * 5 + q) * 512 + l * 8, pool + (w * 5 + q) * 1024);

  // ---- stage e_i (16 rows) + e_j (16 rows) bf16, chunk-XOR swizzled ----
#pragma unroll
  for (int q = 0; q < 12; ++q) {
    int t = tid + 256 * q;                    // 0..3071
    int isI = (t < 1536);
    int tt = isI ? t : t - 1536;
    int r = tt / 96, d = tt - (tt / 96) * 96;
    int sc = d ^ (r & 7);
    const float* src = E + (size_t)((isI ? ibase : jbase) + r) * 768 + sc * 8;
    f32x4 a0 = *(const f32x4*)(src);
    f32x4 a1 = *(const f32x4*)(src + 4);
    bf16x8 v;
#pragma unroll
    for (int e = 0; e < 4; ++e) { v[e] = (__bf16)a0[e]; v[e + 4] = (__bf16)a1[e]; }
    *(bf16x8*)((isI ? eib : ejb) + r * 1536 + d * 16) = v;
  }

  // ---- stage b2/W3 (padded) ----
  if (tid < 160) {
    float* bwf = (float*)(pool + 90112);
    bwf[tid]       = (tid < 150) ? b2[tid] : 0.f;
    bwf[160 + tid] = (tid < 150) ? W3[tid] : 0.f;
  }
  float b3v = b3[0];

  // ---- acc1 init: C1[h = ct*16+kg*4+r][i = m] = A1[i][h]+A2[j][h]+b1[h] ----
  f32x4 acc1[10][4];
#pragma unroll
  for (int ct = 0; ct < 10; ++ct) {
    f32x4 a1v = *(const f32x4*)(A12 + (size_t)(ibase + m) * 320 + ct * 16 + kg * 4);
    f32x4 b1v = *(const f32x4*)(b1p + ct * 16 + kg * 4);
#pragma unroll
    for (int pt = 0; pt < 4; ++pt) {
      f32x4 a2v = *(const f32x4*)(A12 + (size_t)(jbase + w * 4 + pt) * 320 + 160 + ct * 16 + kg * 4);
      acc1[ct][pt] = a1v + a2v + b1v;
    }
  }

  __syncthreads();   // full drain once: slab0 + e-stage + bw all resident

  // ---- GEMM1 compute for one BK=64 slab (2 K=32 steps) ----
  auto compute = [&](int t) {
    const __bf16* wb = (const __bf16*)(pool + (t & 1) * 20480);
#pragma unroll
    for (int s = 0; s < 2; ++s) {
      int cb = t * 8 + s * 4 + kg;            // 16B-chunk index in row
      bf16x8 eiv = *(const bf16x8*)(eib + m * 1536 + ((cb ^ (m & 7)) << 4));
      float eif[8];
#pragma unroll
      for (int e = 0; e < 8; ++e) eif[e] = (float)eiv[e];
      bf16x8 pf[4];
#pragma unroll
      for (int pt = 0; pt < 4; ++pt) {
        int jr = w * 4 + pt;
        bf16x8 ejv = *(const bf16x8*)(ejb + jr * 1536 + ((cb ^ (jr & 7)) << 4));
#pragma unroll
        for (int e = 0; e < 8; ++e)
          pf[pt][e] = (__bf16)(eif[e] * (float)ejv[e]);
      }
#pragma unroll
      for (int ct = 0; ct < 10; ++ct) {
        bf16x8 wf = *(const bf16x8*)(wb + (s * 10 + ct) * 512 + l * 8);
#pragma unroll
        for (int pt = 0; pt < 4; ++pt)
          acc1[ct][pt] = MFMA16(wf, pf[pt], acc1[ct][pt]);
      }
    }
  };

  // ---- GEMM1: 12 rounds, dbuf slabs, counted vmcnt, 2 raw barriers ----
  for (int t = 0; t < 12; ++t) {
    if (t < 11) {
#pragma unroll
      for (int q = 0; q < 5; ++q)
        glds16(W1cp + ((size_t)(t + 1) * 20 + w * 5 + q) * 512 + l * 8,
               pool + ((t + 1) & 1) * 20480 + (w * 5 + q) * 1024);
      asm volatile("s_waitcnt vmcnt(5)" ::: "memory");
    } else {
      asm volatile("s_waitcnt vmcnt(0)" ::: "memory");
    }
    __builtin_amdgcn_s_barrier();
    compute(t);
    __builtin_amdgcn_s_barrier();
  }

  // ---- GEMM2 setup: stage all of W2 (50 frags); h1 for all 4 j-cols ----
  {
    int f0 = (w < 2) ? w * 13 : 26 + (w - 2) * 12;
    int nf = (w < 2) ? 13 : 12;
    for (int q = 0; q < nf; ++q)
      glds16(W2p + (size_t)(f0 + q) * 512 + l * 8, pool + (f0 + q) * 1024);
  }
  // h1 writes (regions dead after GEMM1's trailing barrier; overlaps stage)
#pragma unroll
  for (int pt = 0; pt < 4; ++pt) {
    char* hbp = pool + 51200 + (w * 4 + pt) * 6144;
#pragma unroll
    for (int ct = 0; ct < 10; ++ct) {
      union { __bf16 h[4]; unsigned u[2]; } cv;
      cv.h[0] = (__bf16)fmaxf(acc1[ct][pt][0], 0.f);
      cv.h[1] = (__bf16)fmaxf(acc1[ct][pt][1], 0.f);
      cv.h[2] = (__bf16)fmaxf(acc1[ct][pt][2], 0.f);
      cv.h[3] = (__bf16)fmaxf(acc1[ct][pt][3], 0.f);
      int c = (2 * ct + (kg >> 1)) ^ (m & 7);
      char* dst = hbp + m * 384 + c * 16 + (kg & 1) * 8;
      *(unsigned*)(dst)     = cv.u[0];
      *(unsigned*)(dst + 4) = cv.u[1];
    }
  }
  asm volatile("s_waitcnt vmcnt(0)" ::: "memory");
  __builtin_amdgcn_s_barrier();

  // ---- GEMM2: 5 barrier-free rounds; C2[h2][i] per j-col ----
  f32x4 acc2[10][4];
#pragma unroll
  for (int ct = 0; ct < 10; ++ct)
#pragma unroll
    for (int pt = 0; pt < 4; ++pt) acc2[ct][pt] = (f32x4){0.f, 0.f, 0.f, 0.f};

#pragma unroll
  for (int s = 0; s < 5; ++s) {
    bf16x8 hf[4];
#pragma unroll
    for (int pt = 0; pt < 4; ++pt)
      hf[pt] = *(const bf16x8*)(pool + 51200 + (w * 4 + pt) * 6144 + m * 384 +
                                (((4 * s + kg) ^ (m & 7)) << 4));
#pragma unroll
    for (int ct = 0; ct < 10; ++ct) {
      bf16x8 w2f = *(const bf16x8*)(pool + (s * 10 + ct) * 1024 + l * 16);
#pragma unroll
      for (int pt = 0; pt < 4; ++pt)
        acc2[ct][pt] = MFMA16(w2f, hf[pt], acc2[ct][pt]);
    }
  }

  // ---- epilogue: s = relu(h2+b2)@W3 + b3; reduce over kg; store ----
  const float* bwp = (const float*)(pool + 90112);
#pragma unroll
  for (int pt = 0; pt < 4; ++pt) {
    float sum = 0.f;
#pragma unroll
    for (int ct = 0; ct < 10; ++ct) {
      f32x4 b2q = *(const f32x4*)(bwp + ct * 16 + kg * 4);
      f32x4 w3q = *(const f32x4*)(bwp + 160 + ct * 16 + kg * 4);
#pragma unroll
      for (int r2 = 0; r2 < 4; ++r2)
        sum += fmaxf(acc2[ct][pt][r2] + b2q[r2], 0.f) * w3q[r2];
    }
    sum += __shfl_xor(sum, 16, 64);
    sum += __shfl_xor(sum, 32, 64);
    if (kg == 0) {
      int il = it * 16 + m;
      int jl = jt * 16 + w * 4 + pt;
      if (jl < il)
        out[(size_t)(b * NSEQ + il) * NSEQ + jl] = sum + b3v;
    }
  }
}

// ---------------------------------------------------------------------------
// softmax: 4 (b,i)-rows per block, one wave each.
// ---------------------------------------------------------------------------
__global__ __launch_bounds__(256) void softmax_rows(float* __restrict__ out) {
  int w = threadIdx.x >> 6, l = threadIdx.x & 63;
  int blk = blockIdx.x * 4 + w;   // 0..1535 = b*192+i
  int i = blk % NSEQ;
  size_t base = (size_t)blk * NSEQ;
  float v[3];
  float mx = NEGINF;
#pragma unroll
  for (int t = 0; t < 3; ++t) {
    int j = l + 64 * t;
    float x = (j < i) ? out[base + j] : (j == i ? 0.f : NEGINF);
    v[t] = x;
    mx = fmaxf(mx, x);
  }
#pragma unroll
  for (int off = 32; off >= 1; off >>= 1) mx = fmaxf(mx, __shfl_xor(mx, off, 64));
  float s = 0.f;
#pragma unroll
  for (int t = 0; t < 3; ++t) s += __expf(v[t] - mx);
#pragma unroll
  for (int off = 32; off >= 1; off >>= 1) s += __shfl_xor(s, off, 64);
  float inv = 1.0f / s;
#pragma unroll
  for (int t = 0; t < 3; ++t) {
    int j = l + 64 * t;
    out[base + j] = (j <= i) ? __expf(v[t] - mx) * inv : PADV;
  }
}

// ---------------------------------------------------------------------------
extern "C" void kernel_launch(void* const* d_in, const int* in_sizes, int n_in,
                              void* d_out, int out_size, void* d_ws, size_t ws_size,
                              hipStream_t stream) {
  const float* E  = (const float*)d_in[0];
  const float* W1 = (const float*)d_in[1];
  const float* b1 = (const float*)d_in[2];
  const float* W2 = (const float*)d_in[3];
  const float* b2 = (const float*)d_in[4];
  const float* W3 = (const float*)d_in[5];
  const float* b3 = (const float*)d_in[6];
  float* out = (float*)d_out;

  char* ws = (char*)d_ws;
  float*  A12   = (float*)(ws);                 // 1,966,080 B (491520 f32)
  __bf16* W1abp = (__bf16*)(ws + 1966080);      //   491,520 B
  __bf16* W1cp  = (__bf16*)(ws + 2457600);      //   245,760 B (dense 10-frag)
  __bf16* W2p   = (__bf16*)(ws + 2703360);      //    51,200 B (dense 10-frag)
  float*  b1p   = (float*)(ws + 2754560);       //       640 B

  prep_pack<<<1541, 256, 0, stream>>>(W1, W2, b1, W1abp, W1cp, W2p, b1p, A12);
  prep_gemm<<<768, 256, 0, stream>>>(E, W1abp, A12);
  pair_mlp<<<624, 256, 0, stream>>>(E, A12, W1cp, W2p, b1p, b2, W3, b3, out);
  softmax_rows<<<384, 256, 0, stream>>>(out);
}

// Round 11
// 93.950 us; speedup vs baseline: 2.0085x; 1.1296x over previous
//
#include <hip/hip_runtime.h>
#include <hip/hip_bf16.h>

#define NSEQ   192
#define PADV   -1000.0f
#define NEGINF -1.0e30f

typedef _Float16 f16x8 __attribute__((ext_vector_type(8)));
typedef float    f32x4 __attribute__((ext_vector_type(4)));

__device__ __forceinline__ void glds16(const void* g, void* l) {
  __builtin_amdgcn_global_load_lds(
      (const __attribute__((address_space(1))) unsigned int*)g,
      (__attribute__((address_space(3))) unsigned int*)l, 16, 0, 0);
}

#define MFMA16(a, b, c) __builtin_amdgcn_mfma_f32_16x16x32_f16((a), (b), (c), 0, 0, 0)

// ---------------------------------------------------------------------------
// prep_pack: repack weights into f16 MFMA fragment order (frag: lane l elem e
// holds M[k=(l>>4)*8+e][h=(l&15)+16q]); W1c/W2 as 12-frag padded slices for
// uniform 3-frag/wave staging. Also zeroes A12 and pads b1 -> b1p[160] f32.
// ---------------------------------------------------------------------------
__global__ __launch_bounds__(256) void prep_pack(const float* __restrict__ W1,
                                                 const float* __restrict__ W2,
                                                 const float* __restrict__ b1,
                                                 _Float16* __restrict__ W1abp,
                                                 _Float16* __restrict__ W1cp,
                                                 _Float16* __restrict__ W2p,
                                                 float* __restrict__ b1p,
                                                 float* __restrict__ A12) {
  int idx = blockIdx.x * 256 + threadIdx.x;   // grid 1657*256 = 424192
  if (idx < 245760) { A12[idx] = 0.f; A12[245760 + idx] = 0.f; }

  if (idx < 245760) {                         // W1ab: 24 kk x 20 frags
    int e = idx & 7, l = (idx >> 3) & 63, t = idx >> 9;
    int ct = t % 20, kk = t / 20;
    int k = kk * 32 + ((l >> 4) << 3) + e;    // 0..767
    int hp = ct * 16 + (l & 15);              // 0..319
    int col = (hp < 160) ? hp : hp - 160;
    int rbase = (hp < 160) ? 0 : 768;
    float v = (col < 150) ? W1[(size_t)(rbase + k) * 150 + col] : 0.f;
    W1abp[idx] = (_Float16)v;
  } else if (idx < 393216) {                  // W1c: 24 kk x 12 frags (pad 2)
    int j = idx - 245760;
    int kk = j / 6144, rem = j % 6144;
    int q = rem >> 9, l = (rem >> 3) & 63, e = rem & 7;
    int k = kk * 32 + ((l >> 4) << 3) + e;
    int h = q * 16 + (l & 15);
    float v = (q < 10 && h < 150) ? W1[(size_t)(1536 + k) * 150 + h] : 0.f;
    W1cp[j] = (_Float16)v;
  } else if (idx < 423936) {                  // W2: 5 s x 12 frags (pad 2)
    int j = idx - 393216;
    int s = j / 6144, rem = j % 6144;
    int q = rem >> 9, l = (rem >> 3) & 63, e = rem & 7;
    int k = s * 32 + ((l >> 4) << 3) + e;
    int h = q * 16 + (l & 15);
    float v = (q < 10 && k < 150 && h < 150) ? W2[(size_t)k * 150 + h] : 0.f;
    W2p[j] = (_Float16)v;
  } else if (idx < 424096) {
    int h = idx - 423936;
    b1p[h] = (h < 150) ? b1[h] : 0.f;
  }
}

// ---------------------------------------------------------------------------
// prep_gemm: A12[1536][320] += E @ [W1a|W1b], K split 8 ways (f32 atomics).
// ---------------------------------------------------------------------------
__global__ __launch_bounds__(256) void prep_gemm(const float* __restrict__ E,
                                                 const _Float16* __restrict__ W1abp,
                                                 float* __restrict__ A12) {
  int tid = threadIdx.x;
  int w = tid >> 6, l = tid & 63, m = l & 15, kg = l >> 4;
  int mt = blockIdx.x >> 3;                   // 0..95
  int c  = blockIdx.x & 7;                    // K-chunk 0..7
  const float* ep = E + (size_t)(mt * 16 + m) * 768 + c * 96;

  f32x4 acc[5];
#pragma unroll
  for (int u = 0; u < 5; ++u) acc[u] = (f32x4){0.f, 0.f, 0.f, 0.f};

#pragma unroll
  for (int kk = 0; kk < 3; ++kk) {
    int k = kk * 32 + kg * 8;
    f32x4 x0 = *(const f32x4*)(ep + k);
    f32x4 x1 = *(const f32x4*)(ep + k + 4);
    f16x8 af;
#pragma unroll
    for (int e = 0; e < 4; ++e) { af[e] = (_Float16)x0[e]; af[e + 4] = (_Float16)x1[e]; }
    const f16x8* wp = (const f16x8*)W1abp + (size_t)(((c * 3 + kk) * 20) + w * 5) * 64 + l;
#pragma unroll
    for (int u = 0; u < 5; ++u)
      acc[u] = MFMA16(af, wp[u * 64], acc[u]);
  }
#pragma unroll
  for (int u = 0; u < 5; ++u)
#pragma unroll
    for (int r = 0; r < 4; ++r)
      atomicAdd(&A12[(size_t)(mt * 16 + kg * 4 + r) * 320 + (w * 5 + u) * 16 + m], acc[u][r]);
}

// ---------------------------------------------------------------------------
// pair_mlp r11: 16i x 16j tile (624 blocks), 256 thr / 4 waves, wave w owns
// j-cols {4w..4w+3}. All operands f16: pair pack = 4 v_pk_mul_f16 (no cvts
// in the loop). Swapped GEMM1 C1[h][i], 10 W-reads -> 40 MFMA per step.
// K=32 rounds (24), 12-frag slices, 3 glds/wave, counted vmcnt(3), 2 raw
// barriers/round, NO setprio. 75 KB LDS => 2 blocks/CU. GEMM2: 2 passes x 5
// slices, h1 f16 in dead e-region, W2 slice dbuf; stores deferred.
// ---------------------------------------------------------------------------
__global__ __launch_bounds__(256, 2) void pair_mlp(
    const float* __restrict__ E, const float* __restrict__ A12,
    const _Float16* __restrict__ W1cp, const _Float16* __restrict__ W2p,
    const float* __restrict__ b1p, const float* __restrict__ b2,
    const float* __restrict__ W3, const float* __restrict__ b3,
    float* __restrict__ out) {
  __shared__ alignas(16) char pool[75008];
  // [0,24576)      W slab dbuf: 2 x 12 frags x 1024B
  // [24576,49152)  eib 16 rows x 96 chunks(16B), XOR-swizzled  | phase2: h1
  // [49152,73728)  ejb 16 rows x 96 chunks(16B), XOR-swizzled  | slots 8x6144
  // [73728,75008)  bw: b2f[160], w3f[160] f32
  char* eib = pool + 24576;
  char* ejb = pool + 49152;

  const int tid = threadIdx.x;
  const int w = tid >> 6, l = tid & 63;
  const int m = l & 15, kg = l >> 4;

  // XCD-aware bijective swizzle (624 == 8*78), tri decode (16x16 tiles)
  int bid = blockIdx.x;
  int blk = (bid & 7) * 78 + (bid >> 3);
  int b = blk / 78, r0 = blk - b * 78;
  int it = (int)((sqrtf(8.f * (float)r0 + 1.f) - 1.f) * 0.5f);
  while (it * (it + 1) / 2 > r0) --it;
  while ((it + 1) * (it + 2) / 2 <= r0) ++it;
  int jt = r0 - it * (it + 1) / 2;            // 0..it

  const int ibase = b * NSEQ + it * 16;
  const int jbase = b * NSEQ + jt * 16;

  // ---- stage W1c slice 0 (3 frags/wave) into buf0 ----
#pragma unroll
  for (int q = 0; q < 3; ++q)
    glds16(W1cp + (size_t)(w * 3 + q) * 512 + l * 8, pool + (w * 3 + q) * 1024);

  // ---- stage e_i + e_j as f16, chunk-XOR swizzled ----
#pragma unroll
  for (int q = 0; q < 12; ++q) {
    int t = tid + 256 * q;                    // 0..3071
    int isI = (t < 1536);
    int tt = isI ? t : t - 1536;
    int r = tt / 96, d = tt - (tt / 96) * 96;
    int sc = d ^ (r & 7);
    const float* src = E + (size_t)((isI ? ibase : jbase) + r) * 768 + sc * 8;
    f32x4 a0 = *(const f32x4*)(src);
    f32x4 a1 = *(const f32x4*)(src + 4);
    f16x8 v;
#pragma unroll
    for (int e = 0; e < 4; ++e) { v[e] = (_Float16)a0[e]; v[e + 4] = (_Float16)a1[e]; }
    *(f16x8*)((isI ? eib : ejb) + r * 1536 + d * 16) = v;
  }

  // ---- stage b2/W3 (padded) ----
  if (tid < 160) {
    float* bwf = (float*)(pool + 73728);
    bwf[tid]       = (tid < 150) ? b2[tid] : 0.f;
    bwf[160 + tid] = (tid < 150) ? W3[tid] : 0.f;
  }
  float b3v = b3[0];

  // ---- acc1 init: C1[h = ct*16+kg*4+r][i = m] = A1[i][h]+A2[j][h]+b1[h] ----
  f32x4 acc1[10][4];
#pragma unroll
  for (int ct = 0; ct < 10; ++ct) {
    f32x4 a1v = *(const f32x4*)(A12 + (size_t)(ibase + m) * 320 + ct * 16 + kg * 4);
    f32x4 b1v = *(const f32x4*)(b1p + ct * 16 + kg * 4);
#pragma unroll
    for (int pt = 0; pt < 4; ++pt) {
      f32x4 a2v = *(const f32x4*)(A12 + (size_t)(jbase + w * 4 + pt) * 320 + 160 + ct * 16 + kg * 4);
      acc1[ct][pt] = a1v + a2v + b1v;
    }
  }

  __syncthreads();   // one full drain: slice0 + e-stage + bw resident

  // ---- GEMM1: 24 K=32 rounds; dbuf slabs, counted vmcnt, 2 barriers ----
  for (int t = 0; t < 24; ++t) {
    if (t < 23) {
#pragma unroll
      for (int q = 0; q < 3; ++q)
        glds16(W1cp + ((size_t)(t + 1) * 12 + w * 3 + q) * 512 + l * 8,
               pool + ((t + 1) & 1) * 12288 + (w * 3 + q) * 1024);
      asm volatile("s_waitcnt vmcnt(3)" ::: "memory");
    } else {
      asm volatile("s_waitcnt vmcnt(0)" ::: "memory");
    }
    __builtin_amdgcn_s_barrier();

    const char* wb = pool + (t & 1) * 12288;
    int cb = t * 4 + kg;
    f16x8 eiv = *(const f16x8*)(eib + m * 1536 + ((cb ^ (m & 7)) << 4));
    f16x8 pf[4];
#pragma unroll
    for (int pt = 0; pt < 4; ++pt) {
      int jr = w * 4 + pt;
      f16x8 ejv = *(const f16x8*)(ejb + jr * 1536 + ((cb ^ (jr & 7)) << 4));
      pf[pt] = eiv * ejv;                     // v_pk_mul_f16 x4, no cvts
    }
#pragma unroll
    for (int ct = 0; ct < 10; ++ct) {
      f16x8 wf = *(const f16x8*)(wb + ct * 1024 + l * 16);
#pragma unroll
      for (int pt = 0; pt < 4; ++pt)
        acc1[ct][pt] = MFMA16(wf, pf[pt], acc1[ct][pt]);
    }
    __builtin_amdgcn_s_barrier();
  }

  // ---- GEMM2 setup: stage W2 slice 0; write h1 pass 0 into dead e-region --
  auto write_h1 = [&](int c, int pt) {
    char* hbp = eib + (w * 2 + c) * 6144;     // slot (w,c): 16 rows x 384B
#pragma unroll
    for (int ct = 0; ct < 10; ++ct) {
      union { _Float16 h[4]; unsigned u[2]; } cv;
      cv.h[0] = (_Float16)fmaxf(acc1[ct][pt][0], 0.f);
      cv.h[1] = (_Float16)fmaxf(acc1[ct][pt][1], 0.f);
      cv.h[2] = (_Float16)fmaxf(acc1[ct][pt][2], 0.f);
      cv.h[3] = (_Float16)fmaxf(acc1[ct][pt][3], 0.f);
      int cc = (2 * ct + (kg >> 1)) ^ (m & 7);
      char* dst = hbp + m * 384 + cc * 16 + (kg & 1) * 8;
      *(unsigned*)(dst)     = cv.u[0];
      *(unsigned*)(dst + 4) = cv.u[1];
    }
  };

#pragma unroll
  for (int q = 0; q < 3; ++q)
    glds16(W2p + (size_t)(w * 3 + q) * 512 + l * 8, pool + (w * 3 + q) * 1024);
  write_h1(0, 0);
  write_h1(1, 1);

  f32x4 acc2[10][2];
  float sums[2][2];

  // ---- GEMM2: 10 rounds = 2 passes x 5 slices ----
#pragma unroll
  for (int r = 0; r < 10; ++r) {
    const int p = r / 5, s = r - p * 5;
    if (r < 9) {
      int ns = (r + 1 >= 5) ? r + 1 - 5 : r + 1;
#pragma unroll
      for (int q = 0; q < 3; ++q)
        glds16(W2p + ((size_t)ns * 12 + w * 3 + q) * 512 + l * 8,
               pool + ((r + 1) & 1) * 12288 + (w * 3 + q) * 1024);
      asm volatile("s_waitcnt vmcnt(3)" ::: "memory");
    } else {
      asm volatile("s_waitcnt vmcnt(0)" ::: "memory");
    }
    __builtin_amdgcn_s_barrier();

    if (r == 5) { write_h1(0, 2); write_h1(1, 3); }
    if (s == 0) {
#pragma unroll
      for (int ct = 0; ct < 10; ++ct) {
        acc2[ct][0] = (f32x4){0.f, 0.f, 0.f, 0.f};
        acc2[ct][1] = (f32x4){0.f, 0.f, 0.f, 0.f};
      }
    }

    const char* wb = pool + (r & 1) * 12288;
    f16x8 hf[2];
#pragma unroll
    for (int c = 0; c < 2; ++c)
      hf[c] = *(const f16x8*)(eib + (w * 2 + c) * 6144 + m * 384 +
                              (((4 * s + kg) ^ (m & 7)) << 4));
#pragma unroll
    for (int ct = 0; ct < 10; ++ct) {
      f16x8 wf = *(const f16x8*)(wb + ct * 1024 + l * 16);
      acc2[ct][0] = MFMA16(wf, hf[0], acc2[ct][0]);
      acc2[ct][1] = MFMA16(wf, hf[1], acc2[ct][1]);
    }

    if (s == 4) {   // pass epilogue: fold + cross-kg reduce (stores deferred)
      const float* bwp = (const float*)(pool + 73728);
#pragma unroll
      for (int c = 0; c < 2; ++c) {
        float sum = 0.f;
#pragma unroll
        for (int ct = 0; ct < 10; ++ct) {
          f32x4 b2q = *(const f32x4*)(bwp + ct * 16 + kg * 4);
          f32x4 w3q = *(const f32x4*)(bwp + 160 + ct * 16 + kg * 4);
#pragma unroll
          for (int r2 = 0; r2 < 4; ++r2)
            sum += fmaxf(acc2[ct][c][r2] + b2q[r2], 0.f) * w3q[r2];
        }
        sum += __shfl_xor(sum, 16, 64);
        sum += __shfl_xor(sum, 32, 64);
        sums[p][c] = sum;
      }
    }
    __builtin_amdgcn_s_barrier();
  }

  // ---- deferred stores ----
  if (kg == 0) {
    int il = it * 16 + m;
#pragma unroll
    for (int p = 0; p < 2; ++p)
#pragma unroll
      for (int c = 0; c < 2; ++c) {
        int jl = jt * 16 + w * 4 + p * 2 + c;
        if (jl < il)
          out[(size_t)(b * NSEQ + il) * NSEQ + jl] = sums[p][c] + b3v;
      }
  }
}

// ---------------------------------------------------------------------------
// softmax: 4 (b,i)-rows per block, one wave each.
// ---------------------------------------------------------------------------
__global__ __launch_bounds__(256) void softmax_rows(float* __restrict__ out) {
  int w = threadIdx.x >> 6, l = threadIdx.x & 63;
  int blk = blockIdx.x * 4 + w;   // 0..1535 = b*192+i
  int i = blk % NSEQ;
  size_t base = (size_t)blk * NSEQ;
  float v[3];
  float mx = NEGINF;
#pragma unroll
  for (int t = 0; t < 3; ++t) {
    int j = l + 64 * t;
    float x = (j < i) ? out[base + j] : (j == i ? 0.f : NEGINF);
    v[t] = x;
    mx = fmaxf(mx, x);
  }
#pragma unroll
  for (int off = 32; off >= 1; off >>= 1) mx = fmaxf(mx, __shfl_xor(mx, off, 64));
  float s = 0.f;
#pragma unroll
  for (int t = 0; t < 3; ++t) s += __expf(v[t] - mx);
#pragma unroll
  for (int off = 32; off >= 1; off >>= 1) s += __shfl_xor(s, off, 64);
  float inv = 1.0f / s;
#pragma unroll
  for (int t = 0; t < 3; ++t) {
    int j = l + 64 * t;
    out[base + j] = (j <= i) ? __expf(v[t] - mx) * inv : PADV;
  }
}

// ---------------------------------------------------------------------------
extern "C" void kernel_launch(void* const* d_in, const int* in_sizes, int n_in,
                              void* d_out, int out_size, void* d_ws, size_t ws_size,
                              hipStream_t stream) {
  const float* E  = (const float*)d_in[0];
  const float* W1 = (const float*)d_in[1];
  const float* b1 = (const float*)d_in[2];
  const float* W2 = (const float*)d_in[3];
  const float* b2 = (const float*)d_in[4];
  const float* W3 = (const float*)d_in[5];
  const float* b3 = (const float*)d_in[6];
  float* out = (float*)d_out;

  char* ws = (char*)d_ws;
  float*    A12   = (float*)(ws);               // 1,966,080 B (491520 f32)
  _Float16* W1abp = (_Float16*)(ws + 1966080);  //   491,520 B
  _Float16* W1cp  = (_Float16*)(ws + 2457600);  //   294,912 B (12-frag pad)
  _Float16* W2p   = (_Float16*)(ws + 2752512);  //    61,440 B (12-frag pad)
  float*    b1p   = (float*)(ws + 2813952);     //       640 B

  prep_pack<<<1657, 256, 0, stream>>>(W1, W2, b1, W1abp, W1cp, W2p, b1p, A12);
  prep_gemm<<<768, 256, 0, stream>>>(E, W1abp, A12);
  pair_mlp<<<624, 256, 0, stream>>>(E, A12, W1cp, W2p, b1p, b2, W3, b3, out);
  softmax_rows<<<384, 256, 0, stream>>>(out);
}